// Round 2
// baseline (663.426 us; speedup 1.0000x reference)
//
#include <hip/hip_runtime.h>
#include <hip/hip_bf16.h>

// DGCNN forward: 3×GCNConv(+score convs) -> SortPool(k=30) -> Conv1d stack -> MLP
// Fixed problem geometry from the reference setup.
#define NN 50000
#define EE 600000
#define FIN 128
#define GG 500
#define NPG 100
#define KK 30

// ---------------- graph prep ----------------
__global__ void psg_deg(const int* __restrict__ dst, int* __restrict__ deg, int e) {
    int i = blockIdx.x * blockDim.x + threadIdx.x;
    if (i < e) atomicAdd(&deg[dst[i]], 1);
}

__global__ void psg_dinv(const int* __restrict__ deg, float* __restrict__ dinv, int n) {
    int i = blockIdx.x * blockDim.x + threadIdx.x;
    if (i < n) dinv[i] = 1.0f / sqrtf((float)(deg[i] + 1));  // +1 self loop
}

// ---------------- GEMM: hs = (X @ W) * dinv ; acc = hs (self-loop init) ----------------
template <int KD>
__global__ __launch_bounds__(256) void psg_gemm(const float* __restrict__ X,
                                                const float* __restrict__ W,
                                                const float* __restrict__ dinv,
                                                float* __restrict__ hs,
                                                float* __restrict__ acc, int n) {
    __shared__ float Xl[16][KD];
    __shared__ float Wl[KD * 64];
    int t = threadIdx.x;
    int r0 = blockIdx.x * 16;
    for (int i = t; i < KD * 64; i += 256) Wl[i] = W[i];
    for (int i = t; i < 16 * KD; i += 256) {
        int r = i / KD, k = i % KD;
        int row = r0 + r;
        Xl[r][k] = (row < n) ? X[(size_t)row * KD + k] : 0.f;
    }
    __syncthreads();
    int j = t & 63, q = t >> 6;
    float a0 = 0.f, a1 = 0.f, a2 = 0.f, a3 = 0.f;
#pragma unroll 8
    for (int k = 0; k < KD; k++) {
        float w = Wl[k * 64 + j];
        a0 += Xl[q * 4 + 0][k] * w;
        a1 += Xl[q * 4 + 1][k] * w;
        a2 += Xl[q * 4 + 2][k] * w;
        a3 += Xl[q * 4 + 3][k] * w;
    }
    float av[4] = {a0, a1, a2, a3};
#pragma unroll
    for (int rr = 0; rr < 4; rr++) {
        int row = r0 + q * 4 + rr;
        if (row < n) {
            float v = av[rr] * dinv[row];
            hs[(size_t)row * 64 + j] = v;
            acc[(size_t)row * 64 + j] = v;
        }
    }
}

// ---------------- 64-wide edge scatter: acc[dst] += hs[src] ----------------
__global__ __launch_bounds__(256) void psg_scatter64(const int* __restrict__ src,
                                                     const int* __restrict__ dst,
                                                     const float* __restrict__ hs,
                                                     float* __restrict__ acc, int e) {
    int w = (int)((blockIdx.x * 256 + threadIdx.x) >> 6);
    int lane = threadIdx.x & 63;
    if (w < e) {
        int s = src[w], d = dst[w];
        atomicAdd(&acc[(size_t)d * 64 + lane], hs[(size_t)s * 64 + lane]);
    }
}

// ---------------- finish: h = relu(acc*dinv + b); fused 64->1 dot(s) for score convs ----------------
__global__ __launch_bounds__(256) void psg_finish(const float* __restrict__ acc,
                                                  const float* __restrict__ dinv,
                                                  const float* __restrict__ b,
                                                  float* __restrict__ h,
                                                  const float* __restrict__ wva,
                                                  float* __restrict__ sa_src, float* __restrict__ sa_acc,
                                                  const float* __restrict__ wvb,
                                                  float* __restrict__ sb_src, float* __restrict__ sb_acc,
                                                  int n) {
    size_t idx = (size_t)blockIdx.x * 256 + threadIdx.x;
    int node = (int)(idx >> 6), j = (int)(idx & 63);
    if (node >= n) return;
    float di = dinv[node];
    float v = fmaxf(acc[idx] * di + b[j], 0.f);
    h[idx] = v;
    // dot A (always present)
    float ta = v * wva[j];
#pragma unroll
    for (int o = 32; o; o >>= 1) ta += __shfl_xor(ta, o, 64);
    if (j == 0) {
        float tt = ta * di;
        sa_src[node] = tt;
        sa_acc[node] = tt;
    }
    if (wvb) {
        float tb = v * wvb[j];
#pragma unroll
        for (int o = 32; o; o >>= 1) tb += __shfl_xor(tb, o, 64);
        if (j == 0) {
            float tt = tb * di;
            sb_src[node] = tt;
            sb_acc[node] = tt;
        }
    }
}

// ---------------- scalar edge scatter (1 or 2 channels) ----------------
__global__ void psg_scat1(const int* __restrict__ src, const int* __restrict__ dst,
                          const float* __restrict__ a_src, float* __restrict__ a_acc,
                          const float* __restrict__ b_src, float* __restrict__ b_acc, int e) {
    int i = blockIdx.x * blockDim.x + threadIdx.x;
    if (i < e) {
        int s = src[i], d = dst[i];
        atomicAdd(&a_acc[d], a_src[s]);
        if (b_src) atomicAdd(&b_acc[d], b_src[s]);
    }
}

// ---------------- x_out = (s_acc*dinv + bs) * h  (broadcast over 64 ch) ----------------
__global__ void psg_xmul(const float* __restrict__ s_acc, const float* __restrict__ dinv,
                         const float* __restrict__ bs, const float* __restrict__ h,
                         float* __restrict__ xout, int n) {
    size_t idx = (size_t)blockIdx.x * blockDim.x + threadIdx.x;
    int node = (int)(idx >> 6);
    if (node < n) xout[idx] = (s_acc[node] * dinv[node] + bs[0]) * h[idx];
}

// ---------------- h3 = relu(sC_acc*dinv + b3); u = h3*Ws3*dinv ----------------
__global__ void psg_h3(const float* __restrict__ sC_acc, const float* __restrict__ dinv,
                       const float* __restrict__ b3, const float* __restrict__ Ws3,
                       float* __restrict__ h3, float* __restrict__ u_src, float* __restrict__ u_acc,
                       int n) {
    int i = blockIdx.x * blockDim.x + threadIdx.x;
    if (i < n) {
        float di = dinv[i];
        float v = fmaxf(sC_acc[i] * di + b3[0], 0.f);
        h3[i] = v;
        float u = v * Ws3[0] * di;
        u_src[i] = u;
        u_acc[i] = u;
    }
}

// ---------------- sort-pool (x3 computed in-block): stable DESC total-order sort, top-30 ----------------
// JAX lax.sort uses a float->int total-order transform, so -0.0 < +0.0 STRICTLY.
__device__ __forceinline__ int psg_f2ord(float f) {
    int s = __float_as_int(f);
    return s < 0 ? (s ^ 0x7fffffff) : s;
}

__global__ __launch_bounds__(128) void psg_sortpool(const float* __restrict__ u_acc,
                                                    const float* __restrict__ dinv,
                                                    const float* __restrict__ bs3,
                                                    const float* __restrict__ h3,
                                                    const float* __restrict__ x1,
                                                    const float* __restrict__ x2,
                                                    float* __restrict__ pooled) {
    int g = blockIdx.x, t = threadIdx.x;
    __shared__ float key[NPG];
    __shared__ int ord[NPG];
    __shared__ int sel[KK];
    if (t < NPG) {
        int node = g * NPG + t;
        float v = (u_acc[node] * dinv[node] + bs3[0]) * h3[node];  // x3 (keeps ±0 sign!)
        key[t] = v;
        ord[t] = psg_f2ord(v);
    }
    __syncthreads();
    if (t < NPG) {
        int v = ord[t];
        int r = 0;
        for (int m = 0; m < NPG; m++) {
            int u = ord[m];
            r += (u > v) || (u == v && m < t);  // stable descending, total order
        }
        if (r < KK) sel[r] = t;
    }
    __syncthreads();
    for (int r = 0; r < KK; r++) {
        int loc = sel[r];
        int node = g * NPG + loc;
        size_t base = ((size_t)g * KK + r) * 129;
        if (t < 64) pooled[base + t] = x1[(size_t)node * 64 + t];
        else if (t < 128) pooled[base + t] = x2[(size_t)node * 64 + (t - 64)];
        if (t == 0) pooled[base + 128] = key[loc];
    }
}

// ---------------- CNN + MLP head, one block per graph ----------------
__global__ __launch_bounds__(128) void psg_cnn(const float* __restrict__ pooled,
                                               const float* __restrict__ Wc1, const float* __restrict__ bc1,
                                               const float* __restrict__ Wc2, const float* __restrict__ bc2,
                                               const float* __restrict__ Wl1, const float* __restrict__ bl1,
                                               const float* __restrict__ Wl2, const float* __restrict__ bl2,
                                               float* __restrict__ out) {
    int g = blockIdx.x, t = threadIdx.x;
    __shared__ float pl[KK * 129];       // 3870
    __shared__ float wc1[16 * 129];      // 2064
    __shared__ float wc2[32 * 16 * 5];   // 2560
    __shared__ float c1[16 * KK];        // 480
    __shared__ float mp[16 * 15];        // 240
    __shared__ float c2s[352];
    __shared__ float hdds[128];
    __shared__ float red[2];
    for (int i = t; i < KK * 129; i += 128) pl[i] = pooled[(size_t)g * KK * 129 + i];
    for (int i = t; i < 16 * 129; i += 128) wc1[i] = Wc1[i];
    for (int i = t; i < 32 * 16 * 5; i += 128) wc2[i] = Wc2[i];
    __syncthreads();
    // conv1d(1->16, k=129, stride=129) + relu
    for (int idx = t; idx < 16 * KK; idx += 128) {
        int c = idx / KK, k = idx % KK;
        float a = bc1[c];
        for (int d = 0; d < 129; d++) a += pl[k * 129 + d] * wc1[c * 129 + d];
        c1[c * KK + k] = fmaxf(a, 0.f);
    }
    __syncthreads();
    // maxpool1d(2,2)
    for (int idx = t; idx < 16 * 15; idx += 128) {
        int c = idx / 15, k = idx % 15;
        mp[idx] = fmaxf(c1[c * KK + 2 * k], c1[c * KK + 2 * k + 1]);
    }
    __syncthreads();
    // conv1d(16->32, k=5, valid) + relu
    for (int idx = t; idx < 352; idx += 128) {
        int o = idx / 11, k = idx % 11;
        float a = bc2[o];
        for (int i2 = 0; i2 < 16; i2++) {
#pragma unroll
            for (int k2 = 0; k2 < 5; k2++) a += mp[i2 * 15 + k + k2] * wc2[(o * 16 + i2) * 5 + k2];
        }
        c2s[o * 11 + k] = fmaxf(a, 0.f);
    }
    __syncthreads();
    // linear 352 -> 128 + relu
    {
        float a = bl1[t];
        const float* wr = Wl1 + (size_t)t * 352;
        for (int f = 0; f < 352; f++) a += c2s[f] * wr[f];
        hdds[t] = fmaxf(a, 0.f);
    }
    __syncthreads();
    // linear 128 -> 1
    float p = hdds[t] * Wl2[t];
#pragma unroll
    for (int o = 32; o; o >>= 1) p += __shfl_xor(p, o, 64);
    if ((t & 63) == 0) red[t >> 6] = p;
    __syncthreads();
    if (t == 0) out[g] = red[0] + red[1] + bl2[0];
}

extern "C" void kernel_launch(void* const* d_in, const int* in_sizes, int n_in,
                              void* d_out, int out_size, void* d_ws, size_t ws_size,
                              hipStream_t stream) {
    const float* x   = (const float*)d_in[0];
    const int*   ei  = (const int*)d_in[1];
    const float* W1  = (const float*)d_in[2];
    const float* b1  = (const float*)d_in[3];
    const float* W2  = (const float*)d_in[4];
    const float* b2  = (const float*)d_in[5];
    const float* W3  = (const float*)d_in[6];
    const float* b3  = (const float*)d_in[7];
    const float* Ws1 = (const float*)d_in[8];
    const float* bs1 = (const float*)d_in[9];
    const float* Ws2 = (const float*)d_in[10];
    const float* bs2 = (const float*)d_in[11];
    const float* Ws3 = (const float*)d_in[12];
    const float* bs3 = (const float*)d_in[13];
    const float* Wc1 = (const float*)d_in[14];
    const float* bc1 = (const float*)d_in[15];
    const float* Wc2 = (const float*)d_in[16];
    const float* bc2 = (const float*)d_in[17];
    const float* Wl1 = (const float*)d_in[18];
    const float* bl1 = (const float*)d_in[19];
    const float* Wl2 = (const float*)d_in[20];
    const float* bl2 = (const float*)d_in[21];
    float* out = (float*)d_out;

    const int n = in_sizes[0] / FIN;      // 50000
    const int e = in_sizes[1] / 2;        // 600000
    const int* src = ei;
    const int* dst = ei + e;

    // workspace carve-up (~80 MB)
    char* w = (char*)d_ws;
    float* dinv   = (float*)w; w += (size_t)n * 4;
    float* sA_src = (float*)w; w += (size_t)n * 4;
    float* sA_acc = (float*)w; w += (size_t)n * 4;
    float* sB_src = (float*)w; w += (size_t)n * 4;
    float* sB_acc = (float*)w; w += (size_t)n * 4;
    float* sC_src = (float*)w; w += (size_t)n * 4;
    float* sC_acc = (float*)w; w += (size_t)n * 4;
    float* h3     = (float*)w; w += (size_t)n * 4;
    int*   deg    = (int*)w;   w += (size_t)n * 4;
    float* hs     = (float*)w; w += (size_t)n * 64 * 4;
    float* acc    = (float*)w; w += (size_t)n * 64 * 4;
    float* h1     = (float*)w; w += (size_t)n * 64 * 4;
    float* h2     = (float*)w; w += (size_t)n * 64 * 4;
    float* x1     = (float*)w; w += (size_t)n * 64 * 4;
    float* x2     = (float*)w; w += (size_t)n * 64 * 4;
    float* pooled = (float*)w; w += (size_t)GG * KK * 129 * 4;

    const int nb_e   = (e + 255) / 256;
    const int nb_n   = (n + 255) / 256;
    const int nb_g   = (n + 15) / 16;
    const int nb_s64 = (e + 3) / 4;       // 4 edges (waves) per 256-thread block
    const int nb_nl  = (n * 64 + 255) / 256;

    // graph prep
    hipMemsetAsync(deg, 0, (size_t)n * 4, stream);
    psg_deg<<<nb_e, 256, 0, stream>>>(dst, deg, e);
    psg_dinv<<<nb_n, 256, 0, stream>>>(deg, dinv, n);

    // ---- conv1: h1 = relu(Ahat (x W1) + b1); fused dot Ws1 -> sA
    psg_gemm<128><<<nb_g, 256, 0, stream>>>(x, W1, dinv, hs, acc, n);
    psg_scatter64<<<nb_s64, 256, 0, stream>>>(src, dst, hs, acc, e);
    psg_finish<<<nb_nl, 256, 0, stream>>>(acc, dinv, b1, h1, Ws1, sA_src, sA_acc,
                                          nullptr, nullptr, nullptr, n);
    psg_scat1<<<nb_e, 256, 0, stream>>>(src, dst, sA_src, sA_acc, nullptr, nullptr, e);
    psg_xmul<<<nb_nl, 256, 0, stream>>>(sA_acc, dinv, bs1, h1, x1, n);

    // ---- conv2: h2 = relu(Ahat (h1 W2) + b2); fused dots Ws2 -> sB, W3 -> sC
    psg_gemm<64><<<nb_g, 256, 0, stream>>>(h1, W2, dinv, hs, acc, n);
    psg_scatter64<<<nb_s64, 256, 0, stream>>>(src, dst, hs, acc, e);
    psg_finish<<<nb_nl, 256, 0, stream>>>(acc, dinv, b2, h2, Ws2, sB_src, sB_acc,
                                          W3, sC_src, sC_acc, n);
    psg_scat1<<<nb_e, 256, 0, stream>>>(src, dst, sB_src, sB_acc, sC_src, sC_acc, e);
    psg_xmul<<<nb_nl, 256, 0, stream>>>(sB_acc, dinv, bs2, h2, x2, n);

    // ---- conv3 (64->1) and score conv (1->1): sA reused for the 1-ch message
    psg_h3<<<nb_n, 256, 0, stream>>>(sC_acc, dinv, b3, Ws3, h3, sA_src, sA_acc, n);
    psg_scat1<<<nb_e, 256, 0, stream>>>(src, dst, sA_src, sA_acc, nullptr, nullptr, e);

    // ---- sort-pool (computes x3 in-block) + CNN head
    psg_sortpool<<<GG, 128, 0, stream>>>(sA_acc, dinv, bs3, h3, x1, x2, pooled);
    psg_cnn<<<GG, 128, 0, stream>>>(pooled, Wc1, bc1, Wc2, bc2, Wl1, bl1, Wl2, bl2, out);

    (void)n_in; (void)out_size; (void)ws_size;
}

// Round 3
// 435.785 us; speedup vs baseline: 1.5224x; 1.5224x over previous
//
#include <hip/hip_runtime.h>
#include <hip/hip_bf16.h>

// DGCNN forward: 3×GCNConv(+score convs) -> SortPool(k=30) -> Conv1d stack -> MLP
// Round 2: scatter-atomics -> CSR gather (node-centric), fused epilogues.
#define NN 50000
#define EE 600000
#define FIN 128
#define GG 500
#define NPG 100
#define KK 30
#define SCHUNK 1024

// ---------------- graph prep ----------------
__global__ void psg_deg(const int* __restrict__ dst, int* __restrict__ deg, int e) {
    int i = blockIdx.x * blockDim.x + threadIdx.x;
    if (i < e) atomicAdd(&deg[dst[i]], 1);
}

__global__ void psg_dinv(const int* __restrict__ deg, float* __restrict__ dinv, int n) {
    int i = blockIdx.x * blockDim.x + threadIdx.x;
    if (i < n) dinv[i] = 1.0f / sqrtf((float)(deg[i] + 1));  // +1 self loop
}

// exclusive scan of deg -> rowptr, 3 kernels (n=50k, chunks of 1024)
__global__ __launch_bounds__(SCHUNK) void psg_scan1(const int* __restrict__ deg,
                                                    int* __restrict__ rowptr,
                                                    int* __restrict__ csums, int n) {
    __shared__ int sm[SCHUNK];
    int t = threadIdx.x;
    int base = blockIdx.x * SCHUNK;
    int v = (base + t < n) ? deg[base + t] : 0;
    sm[t] = v;
    __syncthreads();
    for (int off = 1; off < SCHUNK; off <<= 1) {
        int u = (t >= off) ? sm[t - off] : 0;
        __syncthreads();
        sm[t] += u;
        __syncthreads();
    }
    if (base + t < n) rowptr[base + t] = sm[t] - v;  // exclusive
    if (t == SCHUNK - 1) csums[blockIdx.x] = sm[t];
}

__global__ void psg_scan2(int* __restrict__ csums, int nb) {  // nb <= 64
    int t = threadIdx.x;
    int v = (t < nb) ? csums[t] : 0;
    int x = v;
#pragma unroll
    for (int off = 1; off < 64; off <<= 1) {
        int u = __shfl_up(x, off, 64);
        if (t >= off) x += u;
    }
    if (t < nb) csums[t] = x - v;  // exclusive
}

__global__ __launch_bounds__(SCHUNK) void psg_scan3(int* __restrict__ rowptr,
                                                    int* __restrict__ rowfill,
                                                    const int* __restrict__ csums,
                                                    int n, int e) {
    int i = blockIdx.x * SCHUNK + threadIdx.x;
    if (i < n) {
        int v = rowptr[i] + csums[blockIdx.x];
        rowptr[i] = v;
        rowfill[i] = v;
    }
    if (i == 0) rowptr[n] = e;
}

// bucket edges by dst: csr_src[pos] = src
__global__ void psg_build(const int* __restrict__ src, const int* __restrict__ dst,
                          int* __restrict__ rowfill, int* __restrict__ csr_src, int e) {
    int i = blockIdx.x * blockDim.x + threadIdx.x;
    if (i < e) {
        int pos = atomicAdd(&rowfill[dst[i]], 1);
        csr_src[pos] = src[i];
    }
}

// ---------------- GEMM: hs = (X @ W) * dinv (message values incl. self) ----------------
template <int KD>
__global__ __launch_bounds__(256) void psg_gemm(const float* __restrict__ X,
                                                const float* __restrict__ W,
                                                const float* __restrict__ dinv,
                                                float* __restrict__ hs, int n) {
    __shared__ float Xl[16][KD];
    __shared__ float Wl[KD * 64];
    int t = threadIdx.x;
    int r0 = blockIdx.x * 16;
    for (int i = t; i < KD * 64; i += 256) Wl[i] = W[i];
    for (int i = t; i < 16 * KD; i += 256) {
        int r = i / KD, k = i % KD;
        int row = r0 + r;
        Xl[r][k] = (row < n) ? X[(size_t)row * KD + k] : 0.f;
    }
    __syncthreads();
    int j = t & 63, q = t >> 6;
    float a0 = 0.f, a1 = 0.f, a2 = 0.f, a3 = 0.f;
#pragma unroll 8
    for (int k = 0; k < KD; k++) {
        float w = Wl[k * 64 + j];
        a0 += Xl[q * 4 + 0][k] * w;
        a1 += Xl[q * 4 + 1][k] * w;
        a2 += Xl[q * 4 + 2][k] * w;
        a3 += Xl[q * 4 + 3][k] * w;
    }
    float av[4] = {a0, a1, a2, a3};
#pragma unroll
    for (int rr = 0; rr < 4; rr++) {
        int row = r0 + q * 4 + rr;
        if (row < n) hs[(size_t)row * 64 + j] = av[rr] * dinv[row];
    }
}

// ---------------- gather + finish: one wave per node ----------------
// acc = hs[node] + sum_{nbr} hs[nbr]; h = relu(acc*dinv + b); fused 64->1 dots
template <int NDOT>
__global__ __launch_bounds__(256) void psg_gfin(const float* __restrict__ hs,
                                                const int* __restrict__ rowptr,
                                                const int* __restrict__ csr_src,
                                                const float* __restrict__ dinv,
                                                const float* __restrict__ b,
                                                float* __restrict__ h,
                                                const float* __restrict__ wv0,
                                                float* __restrict__ s0_src,
                                                const float* __restrict__ wv1,
                                                float* __restrict__ s1_src, int n) {
    int w = (int)((blockIdx.x * 256 + threadIdx.x) >> 6);
    int j = threadIdx.x & 63;
    if (w >= n) return;
    float a = hs[(size_t)w * 64 + j];  // self loop
    int p0 = rowptr[w], p1 = rowptr[w + 1];
    for (int p = p0; p < p1; ++p) {
        int s = csr_src[p];  // wave-uniform -> scalar broadcast
        a += hs[(size_t)s * 64 + j];
    }
    float di = dinv[w];
    float v = fmaxf(a * di + b[j], 0.f);
    h[(size_t)w * 64 + j] = v;
    float t0 = v * wv0[j];
#pragma unroll
    for (int o = 32; o; o >>= 1) t0 += __shfl_xor(t0, o, 64);
    if (j == 0) s0_src[w] = t0 * di;
    if (NDOT == 2) {
        float t1 = v * wv1[j];
#pragma unroll
        for (int o = 32; o; o >>= 1) t1 += __shfl_xor(t1, o, 64);
        if (j == 0) s1_src[w] = t1 * di;
    }
}

// ---------------- scalar gather + xmul: one wave per node ----------------
// s_acc = s_src[node] + sum_nbr s_src[nbr]; x = (s_acc*dinv + bs) * h
__global__ __launch_bounds__(256) void psg_sgx(const float* __restrict__ s_src,
                                               const int* __restrict__ rowptr,
                                               const int* __restrict__ csr_src,
                                               const float* __restrict__ dinv,
                                               const float* __restrict__ bs,
                                               const float* __restrict__ h,
                                               float* __restrict__ xout, int n) {
    int w = (int)((blockIdx.x * 256 + threadIdx.x) >> 6);
    int j = threadIdx.x & 63;
    if (w >= n) return;
    int p0 = rowptr[w], p1 = rowptr[w + 1];
    float part = (j == 63) ? s_src[w] : 0.f;  // self term on an otherwise-idle lane
    for (int p = p0 + j; p < p1; p += 64) part += s_src[csr_src[p]];
#pragma unroll
    for (int o = 32; o; o >>= 1) part += __shfl_xor(part, o, 64);
    xout[(size_t)w * 64 + j] = (part * dinv[w] + bs[0]) * h[(size_t)w * 64 + j];
}

// ---------------- conv3 (64->1): scalar gather -> h3, u_src ----------------
__global__ void psg_h3g(const float* __restrict__ sc_src,
                        const int* __restrict__ rowptr, const int* __restrict__ csr_src,
                        const float* __restrict__ dinv, const float* __restrict__ b3,
                        const float* __restrict__ Ws3,
                        float* __restrict__ h3, float* __restrict__ u_src, int n) {
    int i = blockIdx.x * blockDim.x + threadIdx.x;
    if (i < n) {
        float a = sc_src[i];
        int p1 = rowptr[i + 1];
        for (int p = rowptr[i]; p < p1; ++p) a += sc_src[csr_src[p]];
        float di = dinv[i];
        float v = fmaxf(a * di + b3[0], 0.f);
        h3[i] = v;
        u_src[i] = v * Ws3[0] * di;
    }
}

// ---------------- sort-pool (x3 gathered in-block): stable DESC total-order sort, top-30 ----------------
// JAX lax.sort uses a float->int total-order transform, so -0.0 < +0.0 STRICTLY.
__device__ __forceinline__ int psg_f2ord(float f) {
    int s = __float_as_int(f);
    return s < 0 ? (s ^ 0x7fffffff) : s;
}

__global__ __launch_bounds__(128) void psg_sortpool(const float* __restrict__ u_src,
                                                    const int* __restrict__ rowptr,
                                                    const int* __restrict__ csr_src,
                                                    const float* __restrict__ dinv,
                                                    const float* __restrict__ bs3,
                                                    const float* __restrict__ h3,
                                                    const float* __restrict__ x1,
                                                    const float* __restrict__ x2,
                                                    float* __restrict__ pooled) {
    int g = blockIdx.x, t = threadIdx.x;
    __shared__ float key[NPG];
    __shared__ int ord[NPG];
    __shared__ int sel[KK];
    if (t < NPG) {
        int node = g * NPG + t;
        float a = u_src[node];
        int p1 = rowptr[node + 1];
        for (int p = rowptr[node]; p < p1; ++p) a += u_src[csr_src[p]];
        float v = (a * dinv[node] + bs3[0]) * h3[node];  // x3 (keeps ±0 sign!)
        key[t] = v;
        ord[t] = psg_f2ord(v);
    }
    __syncthreads();
    if (t < NPG) {
        int v = ord[t];
        int r = 0;
        for (int m = 0; m < NPG; m++) {
            int u = ord[m];
            r += (u > v) || (u == v && m < t);  // stable descending, total order
        }
        if (r < KK) sel[r] = t;
    }
    __syncthreads();
    for (int r = 0; r < KK; r++) {
        int loc = sel[r];
        int node = g * NPG + loc;
        size_t base = ((size_t)g * KK + r) * 129;
        if (t < 64) pooled[base + t] = x1[(size_t)node * 64 + t];
        else if (t < 128) pooled[base + t] = x2[(size_t)node * 64 + (t - 64)];
        if (t == 0) pooled[base + 128] = key[loc];
    }
}

// ---------------- CNN + MLP head, one block per graph ----------------
__global__ __launch_bounds__(128) void psg_cnn(const float* __restrict__ pooled,
                                               const float* __restrict__ Wc1, const float* __restrict__ bc1,
                                               const float* __restrict__ Wc2, const float* __restrict__ bc2,
                                               const float* __restrict__ Wl1, const float* __restrict__ bl1,
                                               const float* __restrict__ Wl2, const float* __restrict__ bl2,
                                               float* __restrict__ out) {
    int g = blockIdx.x, t = threadIdx.x;
    __shared__ float pl[KK * 129];       // 3870
    __shared__ float wc1[16 * 129];      // 2064
    __shared__ float wc2[32 * 16 * 5];   // 2560
    __shared__ float c1[16 * KK];        // 480
    __shared__ float mp[16 * 15];        // 240
    __shared__ float c2s[352];
    __shared__ float hdds[128];
    __shared__ float red[2];
    for (int i = t; i < KK * 129; i += 128) pl[i] = pooled[(size_t)g * KK * 129 + i];
    for (int i = t; i < 16 * 129; i += 128) wc1[i] = Wc1[i];
    for (int i = t; i < 32 * 16 * 5; i += 128) wc2[i] = Wc2[i];
    __syncthreads();
    // conv1d(1->16, k=129, stride=129) + relu
    for (int idx = t; idx < 16 * KK; idx += 128) {
        int c = idx / KK, k = idx % KK;
        float a = bc1[c];
        for (int d = 0; d < 129; d++) a += pl[k * 129 + d] * wc1[c * 129 + d];
        c1[c * KK + k] = fmaxf(a, 0.f);
    }
    __syncthreads();
    // maxpool1d(2,2)
    for (int idx = t; idx < 16 * 15; idx += 128) {
        int c = idx / 15, k = idx % 15;
        mp[idx] = fmaxf(c1[c * KK + 2 * k], c1[c * KK + 2 * k + 1]);
    }
    __syncthreads();
    // conv1d(16->32, k=5, valid) + relu
    for (int idx = t; idx < 352; idx += 128) {
        int o = idx / 11, k = idx % 11;
        float a = bc2[o];
        for (int i2 = 0; i2 < 16; i2++) {
#pragma unroll
            for (int k2 = 0; k2 < 5; k2++) a += mp[i2 * 15 + k + k2] * wc2[(o * 16 + i2) * 5 + k2];
        }
        c2s[o * 11 + k] = fmaxf(a, 0.f);
    }
    __syncthreads();
    // linear 352 -> 128 + relu
    {
        float a = bl1[t];
        const float* wr = Wl1 + (size_t)t * 352;
        for (int f = 0; f < 352; f++) a += c2s[f] * wr[f];
        hdds[t] = fmaxf(a, 0.f);
    }
    __syncthreads();
    // linear 128 -> 1
    float p = hdds[t] * Wl2[t];
#pragma unroll
    for (int o = 32; o; o >>= 1) p += __shfl_xor(p, o, 64);
    if ((t & 63) == 0) red[t >> 6] = p;
    __syncthreads();
    if (t == 0) out[g] = red[0] + red[1] + bl2[0];
}

extern "C" void kernel_launch(void* const* d_in, const int* in_sizes, int n_in,
                              void* d_out, int out_size, void* d_ws, size_t ws_size,
                              hipStream_t stream) {
    const float* x   = (const float*)d_in[0];
    const int*   ei  = (const int*)d_in[1];
    const float* W1  = (const float*)d_in[2];
    const float* b1  = (const float*)d_in[3];
    const float* W2  = (const float*)d_in[4];
    const float* b2  = (const float*)d_in[5];
    const float* W3  = (const float*)d_in[6];
    const float* b3  = (const float*)d_in[7];
    const float* Ws1 = (const float*)d_in[8];
    const float* bs1 = (const float*)d_in[9];
    const float* Ws2 = (const float*)d_in[10];
    const float* bs2 = (const float*)d_in[11];
    const float* Ws3 = (const float*)d_in[12];
    const float* bs3 = (const float*)d_in[13];
    const float* Wc1 = (const float*)d_in[14];
    const float* bc1 = (const float*)d_in[15];
    const float* Wc2 = (const float*)d_in[16];
    const float* bc2 = (const float*)d_in[17];
    const float* Wl1 = (const float*)d_in[18];
    const float* bl1 = (const float*)d_in[19];
    const float* Wl2 = (const float*)d_in[20];
    const float* bl2 = (const float*)d_in[21];
    float* out = (float*)d_out;

    const int n = in_sizes[0] / FIN;      // 50000
    const int e = in_sizes[1] / 2;        // 600000
    const int* src = ei;
    const int* dst = ei + e;
    const int nchunk = (n + SCHUNK - 1) / SCHUNK;  // 49 (<=64 for scan2)

    // workspace carve-up (~70 MB)
    char* w = (char*)d_ws;
    float* dinv    = (float*)w; w += (size_t)n * 4;
    float* sA_src  = (float*)w; w += (size_t)n * 4;
    float* sB_src  = (float*)w; w += (size_t)n * 4;
    float* sC_src  = (float*)w; w += (size_t)n * 4;
    float* h3      = (float*)w; w += (size_t)n * 4;
    float* u_src   = (float*)w; w += (size_t)n * 4;
    int*   deg     = (int*)w;   w += (size_t)n * 4;
    int*   rowptr  = (int*)w;   w += (size_t)(n + 1) * 4;
    int*   rowfill = (int*)w;   w += (size_t)n * 4;
    int*   csums   = (int*)w;   w += 64 * 4;
    int*   csr_src = (int*)w;   w += (size_t)e * 4;
    float* hs      = (float*)w; w += (size_t)n * 64 * 4;
    float* h1      = (float*)w; w += (size_t)n * 64 * 4;
    float* h2      = (float*)w; w += (size_t)n * 64 * 4;
    float* x1      = (float*)w; w += (size_t)n * 64 * 4;
    float* x2      = (float*)w; w += (size_t)n * 64 * 4;
    float* pooled  = (float*)w; w += (size_t)GG * KK * 129 * 4;

    const int nb_e  = (e + 255) / 256;
    const int nb_n  = (n + 255) / 256;
    const int nb_g  = (n + 15) / 16;
    const int nb_nw = (n * 64 + 255) / 256;  // one wave per node

    // graph prep: deg -> rowptr (scan) -> CSR build; dinv
    hipMemsetAsync(deg, 0, (size_t)n * 4, stream);
    psg_deg<<<nb_e, 256, 0, stream>>>(dst, deg, e);
    psg_scan1<<<nchunk, SCHUNK, 0, stream>>>(deg, rowptr, csums, n);
    psg_scan2<<<1, 64, 0, stream>>>(csums, nchunk);
    psg_scan3<<<nchunk, SCHUNK, 0, stream>>>(rowptr, rowfill, csums, n, e);
    psg_build<<<nb_e, 256, 0, stream>>>(src, dst, rowfill, csr_src, e);
    psg_dinv<<<nb_n, 256, 0, stream>>>(deg, dinv, n);

    // ---- conv1: h1 = relu(Ahat (x W1) + b1); fused dot Ws1 -> sA_src
    psg_gemm<128><<<nb_g, 256, 0, stream>>>(x, W1, dinv, hs, n);
    psg_gfin<1><<<nb_nw, 256, 0, stream>>>(hs, rowptr, csr_src, dinv, b1, h1,
                                           Ws1, sA_src, nullptr, nullptr, n);
    psg_sgx<<<nb_nw, 256, 0, stream>>>(sA_src, rowptr, csr_src, dinv, bs1, h1, x1, n);

    // ---- conv2: h2 = relu(Ahat (h1 W2) + b2); fused dots Ws2 -> sB, W3 -> sC
    psg_gemm<64><<<nb_g, 256, 0, stream>>>(h1, W2, dinv, hs, n);
    psg_gfin<2><<<nb_nw, 256, 0, stream>>>(hs, rowptr, csr_src, dinv, b2, h2,
                                           Ws2, sB_src, W3, sC_src, n);
    psg_sgx<<<nb_nw, 256, 0, stream>>>(sB_src, rowptr, csr_src, dinv, bs2, h2, x2, n);

    // ---- conv3 (64->1): scalar gather -> h3, u_src (score conv 1->1 message)
    psg_h3g<<<nb_n, 256, 0, stream>>>(sC_src, rowptr, csr_src, dinv, b3, Ws3, h3, u_src, n);

    // ---- sort-pool (gathers u_src, computes x3 in-block) + CNN head
    psg_sortpool<<<GG, 128, 0, stream>>>(u_src, rowptr, csr_src, dinv, bs3, h3, x1, x2, pooled);
    psg_cnn<<<GG, 128, 0, stream>>>(pooled, Wc1, bc1, Wc2, bc2, Wl1, bl1, Wl2, bl2, out);

    (void)n_in; (void)out_size; (void)ws_size;
}

// Round 4
// 371.045 us; speedup vs baseline: 1.7880x; 1.1745x over previous
//
#include <hip/hip_runtime.h>
#include <hip/hip_bf16.h>

// DGCNN forward: 3×GCNConv(+score convs) -> SortPool(k=30) -> Conv1d stack -> MLP
// Round 3: gfin ILP-4 gather, float4-LDS GEMM, fused dinv.
#define NN 50000
#define EE 600000
#define FIN 128
#define GG 500
#define NPG 100
#define KK 30
#define SCHUNK 1024

// ---------------- graph prep ----------------
__global__ void psg_deg(const int* __restrict__ dst, int* __restrict__ deg, int e) {
    int i = blockIdx.x * blockDim.x + threadIdx.x;
    if (i < e) atomicAdd(&deg[dst[i]], 1);
}

// exclusive scan of deg -> rowptr (chunked); also computes dinv = (deg+1)^-1/2
__global__ __launch_bounds__(SCHUNK) void psg_scan1(const int* __restrict__ deg,
                                                    int* __restrict__ rowptr,
                                                    int* __restrict__ csums,
                                                    float* __restrict__ dinv, int n) {
    __shared__ int sm[SCHUNK];
    int t = threadIdx.x;
    int base = blockIdx.x * SCHUNK;
    int v = (base + t < n) ? deg[base + t] : 0;
    sm[t] = v;
    __syncthreads();
    for (int off = 1; off < SCHUNK; off <<= 1) {
        int u = (t >= off) ? sm[t - off] : 0;
        __syncthreads();
        sm[t] += u;
        __syncthreads();
    }
    if (base + t < n) {
        rowptr[base + t] = sm[t] - v;  // exclusive
        dinv[base + t] = 1.0f / sqrtf((float)(v + 1));
    }
    if (t == SCHUNK - 1) csums[blockIdx.x] = sm[t];
}

__global__ void psg_scan2(int* __restrict__ csums, int nb) {  // nb <= 64
    int t = threadIdx.x;
    int v = (t < nb) ? csums[t] : 0;
    int x = v;
#pragma unroll
    for (int off = 1; off < 64; off <<= 1) {
        int u = __shfl_up(x, off, 64);
        if (t >= off) x += u;
    }
    if (t < nb) csums[t] = x - v;  // exclusive
}

__global__ __launch_bounds__(SCHUNK) void psg_scan3(int* __restrict__ rowptr,
                                                    int* __restrict__ rowfill,
                                                    const int* __restrict__ csums,
                                                    int n, int e) {
    int i = blockIdx.x * SCHUNK + threadIdx.x;
    if (i < n) {
        int v = rowptr[i] + csums[blockIdx.x];
        rowptr[i] = v;
        rowfill[i] = v;
    }
    if (i == 0) rowptr[n] = e;
}

// bucket edges by dst: csr_src[pos] = src
__global__ void psg_build(const int* __restrict__ src, const int* __restrict__ dst,
                          int* __restrict__ rowfill, int* __restrict__ csr_src, int e) {
    int i = blockIdx.x * blockDim.x + threadIdx.x;
    if (i < e) {
        int pos = atomicAdd(&rowfill[dst[i]], 1);
        csr_src[pos] = src[i];
    }
}

// ---------------- GEMM: hs = (X @ W) * dinv ----------------
// LDS: X tile (16 rows) + W transposed into float4-per-(k/4, j) for ds_read_b128.
template <int KD>
__global__ __launch_bounds__(256) void psg_gemm(const float* __restrict__ X,
                                                const float* __restrict__ W,
                                                const float* __restrict__ dinv,
                                                float* __restrict__ hs, int n) {
    __shared__ __align__(16) float Xl[16][KD];
    __shared__ __align__(16) float WtF[(KD / 4) * 64 * 4];
    int t = threadIdx.x;
    int r0 = blockIdx.x * 16;
    // stage W transposed: WtF[((k>>2)*64 + j)*4 + (k&3)] = W[k*64+j]
    for (int i = t; i < KD * 64; i += 256) {
        int k = i >> 6, j = i & 63;
        WtF[(((k >> 2) * 64 + j) << 2) + (k & 3)] = W[i];
    }
    // stage X tile (vectorized)
    for (int i4 = t; i4 < 16 * (KD / 4); i4 += 256) {
        int r = i4 / (KD / 4), u = i4 % (KD / 4);
        int row = r0 + r;
        float4 v = make_float4(0.f, 0.f, 0.f, 0.f);
        if (row < n) v = ((const float4*)(X + (size_t)row * KD))[u];
        ((float4*)&Xl[r][0])[u] = v;
    }
    __syncthreads();
    int j = t & 63, q = t >> 6;
    const float4* Wt4 = (const float4*)WtF;
    float a0 = 0.f, a1 = 0.f, a2 = 0.f, a3 = 0.f;
#pragma unroll 4
    for (int u = 0; u < KD / 4; ++u) {
        float4 wv = Wt4[u * 64 + j];
        float4 x0 = *(const float4*)&Xl[q * 4 + 0][u * 4];
        float4 x1 = *(const float4*)&Xl[q * 4 + 1][u * 4];
        float4 x2 = *(const float4*)&Xl[q * 4 + 2][u * 4];
        float4 x3 = *(const float4*)&Xl[q * 4 + 3][u * 4];
        a0 += x0.x * wv.x + x0.y * wv.y + x0.z * wv.z + x0.w * wv.w;
        a1 += x1.x * wv.x + x1.y * wv.y + x1.z * wv.z + x1.w * wv.w;
        a2 += x2.x * wv.x + x2.y * wv.y + x2.z * wv.z + x2.w * wv.w;
        a3 += x3.x * wv.x + x3.y * wv.y + x3.z * wv.z + x3.w * wv.w;
    }
    float av[4] = {a0, a1, a2, a3};
#pragma unroll
    for (int rr = 0; rr < 4; rr++) {
        int row = r0 + q * 4 + rr;
        if (row < n) hs[(size_t)row * 64 + j] = av[rr] * dinv[row];
    }
}

// ---------------- gather + finish: one wave per node, ILP-4 ----------------
// acc = hs[node] + sum_{nbr} hs[nbr]; h = relu(acc*dinv + b); fused 64->1 dots
template <int NDOT>
__global__ __launch_bounds__(256) void psg_gfin(const float* __restrict__ hs,
                                                const int* __restrict__ rowptr,
                                                const int* __restrict__ csr_src,
                                                const float* __restrict__ dinv,
                                                const float* __restrict__ b,
                                                float* __restrict__ h,
                                                const float* __restrict__ wv0,
                                                float* __restrict__ s0_src,
                                                const float* __restrict__ wv1,
                                                float* __restrict__ s1_src, int n) {
    int w = (int)((blockIdx.x * 256 + threadIdx.x) >> 6);
    int j = threadIdx.x & 63;
    if (w >= n) return;
    int p0 = rowptr[w], p1 = rowptr[w + 1];
    float a0 = hs[(size_t)w * 64 + j];  // self loop
    float a1 = 0.f, a2 = 0.f, a3 = 0.f;
    int p = p0;
    for (; p + 4 <= p1; p += 4) {
        int s0 = csr_src[p], s1 = csr_src[p + 1], s2 = csr_src[p + 2], s3 = csr_src[p + 3];
        a0 += hs[(size_t)s0 * 64 + j];
        a1 += hs[(size_t)s1 * 64 + j];
        a2 += hs[(size_t)s2 * 64 + j];
        a3 += hs[(size_t)s3 * 64 + j];
    }
    for (; p < p1; ++p) a1 += hs[(size_t)csr_src[p] * 64 + j];
    float a = (a0 + a1) + (a2 + a3);
    float di = dinv[w];
    float v = fmaxf(a * di + b[j], 0.f);
    h[(size_t)w * 64 + j] = v;
    float t0 = v * wv0[j];
#pragma unroll
    for (int o = 32; o; o >>= 1) t0 += __shfl_xor(t0, o, 64);
    if (j == 0) s0_src[w] = t0 * di;
    if (NDOT == 2) {
        float t1 = v * wv1[j];
#pragma unroll
        for (int o = 32; o; o >>= 1) t1 += __shfl_xor(t1, o, 64);
        if (j == 0) s1_src[w] = t1 * di;
    }
}

// ---------------- scalar gather + xmul: one wave per node ----------------
__global__ __launch_bounds__(256) void psg_sgx(const float* __restrict__ s_src,
                                               const int* __restrict__ rowptr,
                                               const int* __restrict__ csr_src,
                                               const float* __restrict__ dinv,
                                               const float* __restrict__ bs,
                                               const float* __restrict__ h,
                                               float* __restrict__ xout, int n) {
    int w = (int)((blockIdx.x * 256 + threadIdx.x) >> 6);
    int j = threadIdx.x & 63;
    if (w >= n) return;
    int p0 = rowptr[w], p1 = rowptr[w + 1];
    float part = (j == 63) ? s_src[w] : 0.f;  // self term on an otherwise-idle lane
    for (int p = p0 + j; p < p1; p += 64) part += s_src[csr_src[p]];
#pragma unroll
    for (int o = 32; o; o >>= 1) part += __shfl_xor(part, o, 64);
    xout[(size_t)w * 64 + j] = (part * dinv[w] + bs[0]) * h[(size_t)w * 64 + j];
}

// ---------------- conv3 (64->1): scalar gather -> h3, u_src ----------------
__global__ void psg_h3g(const float* __restrict__ sc_src,
                        const int* __restrict__ rowptr, const int* __restrict__ csr_src,
                        const float* __restrict__ dinv, const float* __restrict__ b3,
                        const float* __restrict__ Ws3,
                        float* __restrict__ h3, float* __restrict__ u_src, int n) {
    int i = blockIdx.x * blockDim.x + threadIdx.x;
    if (i < n) {
        float a = sc_src[i];
        int p1 = rowptr[i + 1];
        for (int p = rowptr[i]; p < p1; ++p) a += sc_src[csr_src[p]];
        float di = dinv[i];
        float v = fmaxf(a * di + b3[0], 0.f);
        h3[i] = v;
        u_src[i] = v * Ws3[0] * di;
    }
}

// ---------------- sort-pool: stable DESC total-order sort, top-30 ----------------
// JAX lax.sort uses a float->int total-order transform, so -0.0 < +0.0 STRICTLY.
__device__ __forceinline__ int psg_f2ord(float f) {
    int s = __float_as_int(f);
    return s < 0 ? (s ^ 0x7fffffff) : s;
}

__global__ __launch_bounds__(128) void psg_sortpool(const float* __restrict__ u_src,
                                                    const int* __restrict__ rowptr,
                                                    const int* __restrict__ csr_src,
                                                    const float* __restrict__ dinv,
                                                    const float* __restrict__ bs3,
                                                    const float* __restrict__ h3,
                                                    const float* __restrict__ x1,
                                                    const float* __restrict__ x2,
                                                    float* __restrict__ pooled) {
    int g = blockIdx.x, t = threadIdx.x;
    __shared__ float key[NPG];
    __shared__ int ord[NPG];
    __shared__ int sel[KK];
    if (t < NPG) {
        int node = g * NPG + t;
        float a = u_src[node];
        int p1 = rowptr[node + 1];
        for (int p = rowptr[node]; p < p1; ++p) a += u_src[csr_src[p]];
        float v = (a * dinv[node] + bs3[0]) * h3[node];  // x3 (keeps ±0 sign!)
        key[t] = v;
        ord[t] = psg_f2ord(v);
    }
    __syncthreads();
    if (t < NPG) {
        int v = ord[t];
        int r = 0;
        for (int m = 0; m < NPG; m++) {
            int u = ord[m];
            r += (u > v) || (u == v && m < t);  // stable descending, total order
        }
        if (r < KK) sel[r] = t;
    }
    __syncthreads();
    for (int r = 0; r < KK; r++) {
        int loc = sel[r];
        int node = g * NPG + loc;
        size_t base = ((size_t)g * KK + r) * 129;
        if (t < 64) pooled[base + t] = x1[(size_t)node * 64 + t];
        else if (t < 128) pooled[base + t] = x2[(size_t)node * 64 + (t - 64)];
        if (t == 0) pooled[base + 128] = key[loc];
    }
}

// ---------------- CNN + MLP head, one block per graph ----------------
__global__ __launch_bounds__(128) void psg_cnn(const float* __restrict__ pooled,
                                               const float* __restrict__ Wc1, const float* __restrict__ bc1,
                                               const float* __restrict__ Wc2, const float* __restrict__ bc2,
                                               const float* __restrict__ Wl1, const float* __restrict__ bl1,
                                               const float* __restrict__ Wl2, const float* __restrict__ bl2,
                                               float* __restrict__ out) {
    int g = blockIdx.x, t = threadIdx.x;
    __shared__ float pl[KK * 129];       // 3870
    __shared__ float wc1[16 * 129];      // 2064
    __shared__ float wc2[32 * 16 * 5];   // 2560
    __shared__ float c1[16 * KK];        // 480
    __shared__ float mp[16 * 15];        // 240
    __shared__ float c2s[352];
    __shared__ float hdds[128];
    __shared__ float red[2];
    for (int i = t; i < KK * 129; i += 128) pl[i] = pooled[(size_t)g * KK * 129 + i];
    for (int i = t; i < 16 * 129; i += 128) wc1[i] = Wc1[i];
    for (int i = t; i < 32 * 16 * 5; i += 128) wc2[i] = Wc2[i];
    __syncthreads();
    // conv1d(1->16, k=129, stride=129) + relu
    for (int idx = t; idx < 16 * KK; idx += 128) {
        int c = idx / KK, k = idx % KK;
        float a = bc1[c];
        for (int d = 0; d < 129; d++) a += pl[k * 129 + d] * wc1[c * 129 + d];
        c1[c * KK + k] = fmaxf(a, 0.f);
    }
    __syncthreads();
    // maxpool1d(2,2)
    for (int idx = t; idx < 16 * 15; idx += 128) {
        int c = idx / 15, k = idx % 15;
        mp[idx] = fmaxf(c1[c * KK + 2 * k], c1[c * KK + 2 * k + 1]);
    }
    __syncthreads();
    // conv1d(16->32, k=5, valid) + relu
    for (int idx = t; idx < 352; idx += 128) {
        int o = idx / 11, k = idx % 11;
        float a = bc2[o];
        for (int i2 = 0; i2 < 16; i2++) {
#pragma unroll
            for (int k2 = 0; k2 < 5; k2++) a += mp[i2 * 15 + k + k2] * wc2[(o * 16 + i2) * 5 + k2];
        }
        c2s[o * 11 + k] = fmaxf(a, 0.f);
    }
    __syncthreads();
    // linear 352 -> 128 + relu
    {
        float a = bl1[t];
        const float* wr = Wl1 + (size_t)t * 352;
        for (int f = 0; f < 352; f++) a += c2s[f] * wr[f];
        hdds[t] = fmaxf(a, 0.f);
    }
    __syncthreads();
    // linear 128 -> 1
    float p = hdds[t] * Wl2[t];
#pragma unroll
    for (int o = 32; o; o >>= 1) p += __shfl_xor(p, o, 64);
    if ((t & 63) == 0) red[t >> 6] = p;
    __syncthreads();
    if (t == 0) out[g] = red[0] + red[1] + bl2[0];
}

extern "C" void kernel_launch(void* const* d_in, const int* in_sizes, int n_in,
                              void* d_out, int out_size, void* d_ws, size_t ws_size,
                              hipStream_t stream) {
    const float* x   = (const float*)d_in[0];
    const int*   ei  = (const int*)d_in[1];
    const float* W1  = (const float*)d_in[2];
    const float* b1  = (const float*)d_in[3];
    const float* W2  = (const float*)d_in[4];
    const float* b2  = (const float*)d_in[5];
    const float* W3  = (const float*)d_in[6];
    const float* b3  = (const float*)d_in[7];
    const float* Ws1 = (const float*)d_in[8];
    const float* bs1 = (const float*)d_in[9];
    const float* Ws2 = (const float*)d_in[10];
    const float* bs2 = (const float*)d_in[11];
    const float* Ws3 = (const float*)d_in[12];
    const float* bs3 = (const float*)d_in[13];
    const float* Wc1 = (const float*)d_in[14];
    const float* bc1 = (const float*)d_in[15];
    const float* Wc2 = (const float*)d_in[16];
    const float* bc2 = (const float*)d_in[17];
    const float* Wl1 = (const float*)d_in[18];
    const float* bl1 = (const float*)d_in[19];
    const float* Wl2 = (const float*)d_in[20];
    const float* bl2 = (const float*)d_in[21];
    float* out = (float*)d_out;

    const int n = in_sizes[0] / FIN;      // 50000
    const int e = in_sizes[1] / 2;        // 600000
    const int* src = ei;
    const int* dst = ei + e;
    const int nchunk = (n + SCHUNK - 1) / SCHUNK;  // 49 (<=64 for scan2)

    // workspace carve-up (~70 MB)
    char* w = (char*)d_ws;
    float* dinv    = (float*)w; w += (size_t)n * 4;
    float* sA_src  = (float*)w; w += (size_t)n * 4;
    float* sB_src  = (float*)w; w += (size_t)n * 4;
    float* sC_src  = (float*)w; w += (size_t)n * 4;
    float* h3      = (float*)w; w += (size_t)n * 4;
    float* u_src   = (float*)w; w += (size_t)n * 4;
    int*   deg     = (int*)w;   w += (size_t)n * 4;
    int*   rowptr  = (int*)w;   w += (size_t)(n + 1) * 4;
    int*   rowfill = (int*)w;   w += (size_t)n * 4;
    int*   csums   = (int*)w;   w += 64 * 4;
    int*   csr_src = (int*)w;   w += (size_t)e * 4;
    float* hs      = (float*)w; w += (size_t)n * 64 * 4;
    float* h1      = (float*)w; w += (size_t)n * 64 * 4;
    float* h2      = (float*)w; w += (size_t)n * 64 * 4;
    float* x1      = (float*)w; w += (size_t)n * 64 * 4;
    float* x2      = (float*)w; w += (size_t)n * 64 * 4;
    float* pooled  = (float*)w; w += (size_t)GG * KK * 129 * 4;

    const int nb_e  = (e + 255) / 256;
    const int nb_n  = (n + 255) / 256;
    const int nb_g  = (n + 15) / 16;
    const int nb_nw = (n * 64 + 255) / 256;  // one wave per node

    // graph prep: deg -> rowptr (scan, fused dinv) -> CSR build
    hipMemsetAsync(deg, 0, (size_t)n * 4, stream);
    psg_deg<<<nb_e, 256, 0, stream>>>(dst, deg, e);
    psg_scan1<<<nchunk, SCHUNK, 0, stream>>>(deg, rowptr, csums, dinv, n);
    psg_scan2<<<1, 64, 0, stream>>>(csums, nchunk);
    psg_scan3<<<nchunk, SCHUNK, 0, stream>>>(rowptr, rowfill, csums, n, e);
    psg_build<<<nb_e, 256, 0, stream>>>(src, dst, rowfill, csr_src, e);

    // ---- conv1: h1 = relu(Ahat (x W1) + b1); fused dot Ws1 -> sA_src
    psg_gemm<128><<<nb_g, 256, 0, stream>>>(x, W1, dinv, hs, n);
    psg_gfin<1><<<nb_nw, 256, 0, stream>>>(hs, rowptr, csr_src, dinv, b1, h1,
                                           Ws1, sA_src, nullptr, nullptr, n);
    psg_sgx<<<nb_nw, 256, 0, stream>>>(sA_src, rowptr, csr_src, dinv, bs1, h1, x1, n);

    // ---- conv2: h2 = relu(Ahat (h1 W2) + b2); fused dots Ws2 -> sB, W3 -> sC
    psg_gemm<64><<<nb_g, 256, 0, stream>>>(h1, W2, dinv, hs, n);
    psg_gfin<2><<<nb_nw, 256, 0, stream>>>(hs, rowptr, csr_src, dinv, b2, h2,
                                           Ws2, sB_src, W3, sC_src, n);
    psg_sgx<<<nb_nw, 256, 0, stream>>>(sB_src, rowptr, csr_src, dinv, bs2, h2, x2, n);

    // ---- conv3 (64->1): scalar gather -> h3, u_src (score conv 1->1 message)
    psg_h3g<<<nb_n, 256, 0, stream>>>(sC_src, rowptr, csr_src, dinv, b3, Ws3, h3, u_src, n);

    // ---- sort-pool (gathers u_src, computes x3 in-block) + CNN head
    psg_sortpool<<<GG, 128, 0, stream>>>(u_src, rowptr, csr_src, dinv, bs3, h3, x1, x2, pooled);
    psg_cnn<<<GG, 128, 0, stream>>>(pooled, Wc1, bc1, Wc2, bc2, Wl1, bl1, Wl2, bl2, out);

    (void)n_in; (void)out_size; (void)ws_size;
}

// Round 5
// 355.011 us; speedup vs baseline: 1.8687x; 1.0452x over previous
//
#include <hip/hip_runtime.h>
#include <hip/hip_bf16.h>

// DGCNN forward: 3×GCNConv(+score convs) -> SortPool(k=30) -> Conv1d stack -> MLP
// Round 4: delete sgx kernels (defer x1/x2 to sortpool, top-30 only); gfin ILP-8.
#define NN 50000
#define EE 600000
#define FIN 128
#define GG 500
#define NPG 100
#define KK 30
#define SCHUNK 1024

// ---------------- graph prep ----------------
__global__ void psg_deg(const int* __restrict__ dst, int* __restrict__ deg, int e) {
    int i = blockIdx.x * blockDim.x + threadIdx.x;
    if (i < e) atomicAdd(&deg[dst[i]], 1);
}

// exclusive scan of deg -> rowptr (chunked); also computes dinv = (deg+1)^-1/2
__global__ __launch_bounds__(SCHUNK) void psg_scan1(const int* __restrict__ deg,
                                                    int* __restrict__ rowptr,
                                                    int* __restrict__ csums,
                                                    float* __restrict__ dinv, int n) {
    __shared__ int sm[SCHUNK];
    int t = threadIdx.x;
    int base = blockIdx.x * SCHUNK;
    int v = (base + t < n) ? deg[base + t] : 0;
    sm[t] = v;
    __syncthreads();
    for (int off = 1; off < SCHUNK; off <<= 1) {
        int u = (t >= off) ? sm[t - off] : 0;
        __syncthreads();
        sm[t] += u;
        __syncthreads();
    }
    if (base + t < n) {
        rowptr[base + t] = sm[t] - v;  // exclusive
        dinv[base + t] = 1.0f / sqrtf((float)(v + 1));
    }
    if (t == SCHUNK - 1) csums[blockIdx.x] = sm[t];
}

__global__ void psg_scan2(int* __restrict__ csums, int nb) {  // nb <= 64
    int t = threadIdx.x;
    int v = (t < nb) ? csums[t] : 0;
    int x = v;
#pragma unroll
    for (int off = 1; off < 64; off <<= 1) {
        int u = __shfl_up(x, off, 64);
        if (t >= off) x += u;
    }
    if (t < nb) csums[t] = x - v;  // exclusive
}

__global__ __launch_bounds__(SCHUNK) void psg_scan3(int* __restrict__ rowptr,
                                                    int* __restrict__ rowfill,
                                                    const int* __restrict__ csums,
                                                    int n, int e) {
    int i = blockIdx.x * SCHUNK + threadIdx.x;
    if (i < n) {
        int v = rowptr[i] + csums[blockIdx.x];
        rowptr[i] = v;
        rowfill[i] = v;
    }
    if (i == 0) rowptr[n] = e;
}

// bucket edges by dst: csr_src[pos] = src
__global__ void psg_build(const int* __restrict__ src, const int* __restrict__ dst,
                          int* __restrict__ rowfill, int* __restrict__ csr_src, int e) {
    int i = blockIdx.x * blockDim.x + threadIdx.x;
    if (i < e) {
        int pos = atomicAdd(&rowfill[dst[i]], 1);
        csr_src[pos] = src[i];
    }
}

// ---------------- GEMM: hs = (X @ W) * dinv ----------------
template <int KD>
__global__ __launch_bounds__(256) void psg_gemm(const float* __restrict__ X,
                                                const float* __restrict__ W,
                                                const float* __restrict__ dinv,
                                                float* __restrict__ hs, int n) {
    __shared__ __align__(16) float Xl[16][KD];
    __shared__ __align__(16) float WtF[(KD / 4) * 64 * 4];
    int t = threadIdx.x;
    int r0 = blockIdx.x * 16;
    for (int i = t; i < KD * 64; i += 256) {
        int k = i >> 6, j = i & 63;
        WtF[(((k >> 2) * 64 + j) << 2) + (k & 3)] = W[i];
    }
    for (int i4 = t; i4 < 16 * (KD / 4); i4 += 256) {
        int r = i4 / (KD / 4), u = i4 % (KD / 4);
        int row = r0 + r;
        float4 v = make_float4(0.f, 0.f, 0.f, 0.f);
        if (row < n) v = ((const float4*)(X + (size_t)row * KD))[u];
        ((float4*)&Xl[r][0])[u] = v;
    }
    __syncthreads();
    int j = t & 63, q = t >> 6;
    const float4* Wt4 = (const float4*)WtF;
    float a0 = 0.f, a1 = 0.f, a2 = 0.f, a3 = 0.f;
#pragma unroll 4
    for (int u = 0; u < KD / 4; ++u) {
        float4 wv = Wt4[u * 64 + j];
        float4 x0 = *(const float4*)&Xl[q * 4 + 0][u * 4];
        float4 x1 = *(const float4*)&Xl[q * 4 + 1][u * 4];
        float4 x2 = *(const float4*)&Xl[q * 4 + 2][u * 4];
        float4 x3 = *(const float4*)&Xl[q * 4 + 3][u * 4];
        a0 += x0.x * wv.x + x0.y * wv.y + x0.z * wv.z + x0.w * wv.w;
        a1 += x1.x * wv.x + x1.y * wv.y + x1.z * wv.z + x1.w * wv.w;
        a2 += x2.x * wv.x + x2.y * wv.y + x2.z * wv.z + x2.w * wv.w;
        a3 += x3.x * wv.x + x3.y * wv.y + x3.z * wv.z + x3.w * wv.w;
    }
    float av[4] = {a0, a1, a2, a3};
#pragma unroll
    for (int rr = 0; rr < 4; rr++) {
        int row = r0 + q * 4 + rr;
        if (row < n) hs[(size_t)row * 64 + j] = av[rr] * dinv[row];
    }
}

// ---------------- gather + finish: one wave per node, ILP-8 ----------------
// acc = hs[node] + sum_{nbr} hs[nbr]; h = relu(acc*dinv + b); fused 64->1 dots
template <int NDOT>
__global__ __launch_bounds__(256) void psg_gfin(const float* __restrict__ hs,
                                                const int* __restrict__ rowptr,
                                                const int* __restrict__ csr_src,
                                                const float* __restrict__ dinv,
                                                const float* __restrict__ b,
                                                float* __restrict__ h,
                                                const float* __restrict__ wv0,
                                                float* __restrict__ s0_src,
                                                const float* __restrict__ wv1,
                                                float* __restrict__ s1_src, int n) {
    int w = (int)((blockIdx.x * 256 + threadIdx.x) >> 6);
    int j = threadIdx.x & 63;
    if (w >= n) return;
    int p0 = rowptr[w], p1 = rowptr[w + 1];
    float a0 = hs[(size_t)w * 64 + j];  // self loop
    float a1 = 0.f, a2 = 0.f, a3 = 0.f, a4 = 0.f, a5 = 0.f, a6 = 0.f, a7 = 0.f;
    int p = p0;
    for (; p + 8 <= p1; p += 8) {
        int s0 = csr_src[p],     s1 = csr_src[p + 1], s2 = csr_src[p + 2], s3 = csr_src[p + 3];
        int s4 = csr_src[p + 4], s5 = csr_src[p + 5], s6 = csr_src[p + 6], s7 = csr_src[p + 7];
        a0 += hs[(size_t)s0 * 64 + j];
        a1 += hs[(size_t)s1 * 64 + j];
        a2 += hs[(size_t)s2 * 64 + j];
        a3 += hs[(size_t)s3 * 64 + j];
        a4 += hs[(size_t)s4 * 64 + j];
        a5 += hs[(size_t)s5 * 64 + j];
        a6 += hs[(size_t)s6 * 64 + j];
        a7 += hs[(size_t)s7 * 64 + j];
    }
    if (p + 4 <= p1) {
        int s0 = csr_src[p], s1 = csr_src[p + 1], s2 = csr_src[p + 2], s3 = csr_src[p + 3];
        a4 += hs[(size_t)s0 * 64 + j];
        a5 += hs[(size_t)s1 * 64 + j];
        a6 += hs[(size_t)s2 * 64 + j];
        a7 += hs[(size_t)s3 * 64 + j];
        p += 4;
    }
    for (; p < p1; ++p) a1 += hs[(size_t)csr_src[p] * 64 + j];
    float a = ((a0 + a1) + (a2 + a3)) + ((a4 + a5) + (a6 + a7));
    float di = dinv[w];
    float v = fmaxf(a * di + b[j], 0.f);
    h[(size_t)w * 64 + j] = v;
    float t0 = v * wv0[j];
#pragma unroll
    for (int o = 32; o; o >>= 1) t0 += __shfl_xor(t0, o, 64);
    if (j == 0) s0_src[w] = t0 * di;
    if (NDOT == 2) {
        float t1 = v * wv1[j];
#pragma unroll
        for (int o = 32; o; o >>= 1) t1 += __shfl_xor(t1, o, 64);
        if (j == 0) s1_src[w] = t1 * di;
    }
}

// ---------------- conv3 (64->1): scalar gather -> h3, u_src ----------------
__global__ void psg_h3g(const float* __restrict__ sc_src,
                        const int* __restrict__ rowptr, const int* __restrict__ csr_src,
                        const float* __restrict__ dinv, const float* __restrict__ b3,
                        const float* __restrict__ Ws3,
                        float* __restrict__ h3, float* __restrict__ u_src, int n) {
    int i = blockIdx.x * blockDim.x + threadIdx.x;
    if (i < n) {
        float a = sc_src[i];
        int p1 = rowptr[i + 1];
        for (int p = rowptr[i]; p < p1; ++p) a += sc_src[csr_src[p]];
        float di = dinv[i];
        float v = fmaxf(a * di + b3[0], 0.f);
        h3[i] = v;
        u_src[i] = v * Ws3[0] * di;
    }
}

// ---------------- sort-pool: stable DESC total-order sort, top-30; builds x1/x2 on the fly ----------------
// JAX lax.sort uses a float->int total-order transform, so -0.0 < +0.0 STRICTLY.
__device__ __forceinline__ int psg_f2ord(float f) {
    int s = __float_as_int(f);
    return s < 0 ? (s ^ 0x7fffffff) : s;
}

__global__ __launch_bounds__(128) void psg_sortpool(const float* __restrict__ u_src,
                                                    const int* __restrict__ rowptr,
                                                    const int* __restrict__ csr_src,
                                                    const float* __restrict__ dinv,
                                                    const float* __restrict__ bs1,
                                                    const float* __restrict__ bs2,
                                                    const float* __restrict__ bs3,
                                                    const float* __restrict__ sA_src,
                                                    const float* __restrict__ sB_src,
                                                    const float* __restrict__ h1,
                                                    const float* __restrict__ h2,
                                                    const float* __restrict__ h3,
                                                    float* __restrict__ pooled) {
    int g = blockIdx.x, t = threadIdx.x;
    __shared__ float key[NPG];
    __shared__ int ord[NPG];
    __shared__ int sel[KK];
    __shared__ float sa[KK], sb[KK];
    if (t < NPG) {
        int node = g * NPG + t;
        float a = u_src[node];
        int pe = rowptr[node + 1];
        for (int p = rowptr[node]; p < pe; ++p) a += u_src[csr_src[p]];
        float v = (a * dinv[node] + bs3[0]) * h3[node];  // x3 (keeps ±0 sign!)
        key[t] = v;
        ord[t] = psg_f2ord(v);
    }
    __syncthreads();
    if (t < NPG) {
        int v = ord[t];
        int r = 0;
        for (int m = 0; m < NPG; m++) {
            int u = ord[m];
            r += (u > v) || (u == v && m < t);  // stable descending, total order
        }
        if (r < KK) sel[r] = t;
    }
    __syncthreads();
    // scalar score gathers for the 30 selected nodes: t<32 -> conv A (x1), 32<=t<64 -> conv B (x2)
    {
        int r = t & 31;
        if (t < 64 && r < KK) {
            int node = g * NPG + sel[r];
            const float* ssrc = (t < 32) ? sA_src : sB_src;
            float a = ssrc[node];
            int pe = rowptr[node + 1];
            for (int p = rowptr[node]; p < pe; ++p) a += ssrc[csr_src[p]];
            float scl = a * dinv[node] + ((t < 32) ? bs1[0] : bs2[0]);
            if (t < 32) sa[r] = scl; else sb[r] = scl;
        }
    }
    __syncthreads();
    for (int idx = t; idx < KK * 129; idx += 128) {
        int r = idx / 129, c = idx - r * 129;
        int node = g * NPG + sel[r];
        float v;
        if (c < 64) v = sa[r] * h1[(size_t)node * 64 + c];
        else if (c < 128) v = sb[r] * h2[(size_t)node * 64 + (c - 64)];
        else v = key[sel[r]];
        pooled[((size_t)g * KK + r) * 129 + c] = v;
    }
}

// ---------------- CNN + MLP head, one block per graph ----------------
__global__ __launch_bounds__(128) void psg_cnn(const float* __restrict__ pooled,
                                               const float* __restrict__ Wc1, const float* __restrict__ bc1,
                                               const float* __restrict__ Wc2, const float* __restrict__ bc2,
                                               const float* __restrict__ Wl1, const float* __restrict__ bl1,
                                               const float* __restrict__ Wl2, const float* __restrict__ bl2,
                                               float* __restrict__ out) {
    int g = blockIdx.x, t = threadIdx.x;
    __shared__ float pl[KK * 129];       // 3870
    __shared__ float wc1[16 * 129];      // 2064
    __shared__ float wc2[32 * 16 * 5];   // 2560
    __shared__ float c1[16 * KK];        // 480
    __shared__ float mp[16 * 15];        // 240
    __shared__ float c2s[352];
    __shared__ float hdds[128];
    __shared__ float red[2];
    for (int i = t; i < KK * 129; i += 128) pl[i] = pooled[(size_t)g * KK * 129 + i];
    for (int i = t; i < 16 * 129; i += 128) wc1[i] = Wc1[i];
    for (int i = t; i < 32 * 16 * 5; i += 128) wc2[i] = Wc2[i];
    __syncthreads();
    // conv1d(1->16, k=129, stride=129) + relu
    for (int idx = t; idx < 16 * KK; idx += 128) {
        int c = idx / KK, k = idx % KK;
        float a = bc1[c];
        for (int d = 0; d < 129; d++) a += pl[k * 129 + d] * wc1[c * 129 + d];
        c1[c * KK + k] = fmaxf(a, 0.f);
    }
    __syncthreads();
    // maxpool1d(2,2)
    for (int idx = t; idx < 16 * 15; idx += 128) {
        int c = idx / 15, k = idx % 15;
        mp[idx] = fmaxf(c1[c * KK + 2 * k], c1[c * KK + 2 * k + 1]);
    }
    __syncthreads();
    // conv1d(16->32, k=5, valid) + relu
    for (int idx = t; idx < 352; idx += 128) {
        int o = idx / 11, k = idx % 11;
        float a = bc2[o];
        for (int i2 = 0; i2 < 16; i2++) {
#pragma unroll
            for (int k2 = 0; k2 < 5; k2++) a += mp[i2 * 15 + k + k2] * wc2[(o * 16 + i2) * 5 + k2];
        }
        c2s[o * 11 + k] = fmaxf(a, 0.f);
    }
    __syncthreads();
    // linear 352 -> 128 + relu
    {
        float a = bl1[t];
        const float* wr = Wl1 + (size_t)t * 352;
        for (int f = 0; f < 352; f++) a += c2s[f] * wr[f];
        hdds[t] = fmaxf(a, 0.f);
    }
    __syncthreads();
    // linear 128 -> 1
    float p = hdds[t] * Wl2[t];
#pragma unroll
    for (int o = 32; o; o >>= 1) p += __shfl_xor(p, o, 64);
    if ((t & 63) == 0) red[t >> 6] = p;
    __syncthreads();
    if (t == 0) out[g] = red[0] + red[1] + bl2[0];
}

extern "C" void kernel_launch(void* const* d_in, const int* in_sizes, int n_in,
                              void* d_out, int out_size, void* d_ws, size_t ws_size,
                              hipStream_t stream) {
    const float* x   = (const float*)d_in[0];
    const int*   ei  = (const int*)d_in[1];
    const float* W1  = (const float*)d_in[2];
    const float* b1  = (const float*)d_in[3];
    const float* W2  = (const float*)d_in[4];
    const float* b2  = (const float*)d_in[5];
    const float* W3  = (const float*)d_in[6];
    const float* b3  = (const float*)d_in[7];
    const float* Ws1 = (const float*)d_in[8];
    const float* bs1 = (const float*)d_in[9];
    const float* Ws2 = (const float*)d_in[10];
    const float* bs2 = (const float*)d_in[11];
    const float* Ws3 = (const float*)d_in[12];
    const float* bs3 = (const float*)d_in[13];
    const float* Wc1 = (const float*)d_in[14];
    const float* bc1 = (const float*)d_in[15];
    const float* Wc2 = (const float*)d_in[16];
    const float* bc2 = (const float*)d_in[17];
    const float* Wl1 = (const float*)d_in[18];
    const float* bl1 = (const float*)d_in[19];
    const float* Wl2 = (const float*)d_in[20];
    const float* bl2 = (const float*)d_in[21];
    float* out = (float*)d_out;

    const int n = in_sizes[0] / FIN;      // 50000
    const int e = in_sizes[1] / 2;        // 600000
    const int* src = ei;
    const int* dst = ei + e;
    const int nchunk = (n + SCHUNK - 1) / SCHUNK;  // 49 (<=64 for scan2)

    // workspace carve-up (~45 MB)
    char* w = (char*)d_ws;
    float* dinv    = (float*)w; w += (size_t)n * 4;
    float* sA_src  = (float*)w; w += (size_t)n * 4;
    float* sB_src  = (float*)w; w += (size_t)n * 4;
    float* sC_src  = (float*)w; w += (size_t)n * 4;
    float* h3      = (float*)w; w += (size_t)n * 4;
    float* u_src   = (float*)w; w += (size_t)n * 4;
    int*   deg     = (int*)w;   w += (size_t)n * 4;
    int*   rowptr  = (int*)w;   w += (size_t)(n + 1) * 4;
    int*   rowfill = (int*)w;   w += (size_t)n * 4;
    int*   csums   = (int*)w;   w += 64 * 4;
    int*   csr_src = (int*)w;   w += (size_t)e * 4;
    float* hs      = (float*)w; w += (size_t)n * 64 * 4;
    float* h1      = (float*)w; w += (size_t)n * 64 * 4;
    float* h2      = (float*)w; w += (size_t)n * 64 * 4;
    float* pooled  = (float*)w; w += (size_t)GG * KK * 129 * 4;

    const int nb_e  = (e + 255) / 256;
    const int nb_n  = (n + 255) / 256;
    const int nb_g  = (n + 15) / 16;
    const int nb_nw = (n * 64 + 255) / 256;  // one wave per node

    // graph prep: deg -> rowptr (scan, fused dinv) -> CSR build
    hipMemsetAsync(deg, 0, (size_t)n * 4, stream);
    psg_deg<<<nb_e, 256, 0, stream>>>(dst, deg, e);
    psg_scan1<<<nchunk, SCHUNK, 0, stream>>>(deg, rowptr, csums, dinv, n);
    psg_scan2<<<1, 64, 0, stream>>>(csums, nchunk);
    psg_scan3<<<nchunk, SCHUNK, 0, stream>>>(rowptr, rowfill, csums, n, e);
    psg_build<<<nb_e, 256, 0, stream>>>(src, dst, rowfill, csr_src, e);

    // ---- conv1: h1 = relu(Ahat (x W1) + b1); fused dot Ws1 -> sA_src
    psg_gemm<128><<<nb_g, 256, 0, stream>>>(x, W1, dinv, hs, n);
    psg_gfin<1><<<nb_nw, 256, 0, stream>>>(hs, rowptr, csr_src, dinv, b1, h1,
                                           Ws1, sA_src, nullptr, nullptr, n);

    // ---- conv2: h2 = relu(Ahat (h1 W2) + b2); fused dots Ws2 -> sB, W3 -> sC
    psg_gemm<64><<<nb_g, 256, 0, stream>>>(h1, W2, dinv, hs, n);
    psg_gfin<2><<<nb_nw, 256, 0, stream>>>(hs, rowptr, csr_src, dinv, b2, h2,
                                           Ws2, sB_src, W3, sC_src, n);

    // ---- conv3 (64->1): scalar gather -> h3, u_src (score conv 1->1 message)
    psg_h3g<<<nb_n, 256, 0, stream>>>(sC_src, rowptr, csr_src, dinv, b3, Ws3, h3, u_src, n);

    // ---- sort-pool (gathers u_src -> x3; builds x1/x2 for top-30 only) + CNN head
    psg_sortpool<<<GG, 128, 0, stream>>>(u_src, rowptr, csr_src, dinv, bs1, bs2, bs3,
                                         sA_src, sB_src, h1, h2, h3, pooled);
    psg_cnn<<<GG, 128, 0, stream>>>(pooled, Wc1, bc1, Wc2, bc2, Wl1, bl1, Wl2, bl2, out);

    (void)n_in; (void)out_size; (void)ws_size;
}